// Round 14
// baseline (240.233 us; speedup 1.0000x reference)
//
#include <hip/hip_runtime.h>

#define B_   4
#define T_   2048
#define D_   1024
#define MTOK 8192  // B_*T_

typedef __attribute__((ext_vector_type(8))) _Float16 half8;
typedef __attribute__((ext_vector_type(4))) float    f32x4;

#define GLD(G, L) __builtin_amdgcn_global_load_lds(                       \
    (const __attribute__((address_space(1))) void*)(G),                   \
    (__attribute__((address_space(3))) void*)(L), 16, 0, 0)

#define BAR()   __builtin_amdgcn_s_barrier()
#define BARM()  asm volatile("s_barrier" ::: "memory")
#define LGKM0() do { asm volatile("s_waitcnt lgkmcnt(0)" ::: "memory");   \
                     __builtin_amdgcn_sched_barrier(0); } while (0)
#define VMW(n)  asm volatile("s_waitcnt vmcnt(" #n ")" ::: "memory")

__device__ __forceinline__ unsigned short f2h(float f) {
  return __builtin_bit_cast(unsigned short, (_Float16)f);  // RTE
}
__device__ __forceinline__ float h2f(unsigned short u) {
  return (float)__builtin_bit_cast(_Float16, u);
}

// ---------------- prep: x fp32 -> fp16 (+ zero colsum) --------------
__global__ __launch_bounds__(256) void tofp16_kernel(
    const float4* __restrict__ in, ushort4* __restrict__ out, int n4,
    float4* __restrict__ cs, int c4) {
  int i = blockIdx.x * 256 + threadIdx.x;
  if (i < c4) cs[i] = (float4){0.f, 0.f, 0.f, 0.f};
  if (i >= n4) return;
  float4 v = in[i];
  ushort4 h;
  h.x = f2h(v.x); h.y = f2h(v.y); h.z = f2h(v.z); h.w = f2h(v.w);
  out[i] = h;
}

// ---------------- prep: transpose + concat W -> fp16 ----------------
__global__ __launch_bounds__(256) void wcat_t_kernel(
    const float* __restrict__ Wq, const float* __restrict__ Wk,
    const float* __restrict__ Wv, unsigned short* __restrict__ Wt) {
  __shared__ float tile[32][33];
  int z = blockIdx.z;
  const float* W = (z == 0) ? Wq : ((z == 1) ? Wk : Wv);
  int c0 = blockIdx.x * 32, r0 = blockIdx.y * 32;
  int tx = threadIdx.x & 31, ty = threadIdx.x >> 5;  // 32 x 8
  #pragma unroll
  for (int i = 0; i < 4; ++i)
    tile[ty + i * 8][tx] = W[(size_t)(r0 + ty + i * 8) * D_ + c0 + tx];
  __syncthreads();
  #pragma unroll
  for (int i = 0; i < 4; ++i) {
    float v = tile[tx][ty + i * 8];
    size_t row = (size_t)z * D_ + c0 + ty + i * 8;
    Wt[row * D_ + r0 + tx] = f2h(v);
  }
}

// ---------------- V transpose: QKV cols [2048,3072) -> Vt[b][d][t] --
__global__ __launch_bounds__(256) void vtrans_kernel(
    const unsigned short* __restrict__ QKV, unsigned short* __restrict__ Vt) {
  __shared__ unsigned short tile[64][68];
  int b = blockIdx.z;
  int t0 = blockIdx.x * 64, d0 = blockIdx.y * 64;
  int l16 = threadIdx.x & 15, rr = threadIdx.x >> 4;
  const unsigned short* src =
      QKV + ((size_t)b * 2048 + t0 + rr) * 3072 + 2048 + d0 + l16 * 4;
  #pragma unroll
  for (int i = 0; i < 4; ++i) {
    ushort4 v = *(const ushort4*)(src + (size_t)i * 16 * 3072);
    *(ushort4*)&tile[rr + i * 16][l16 * 4] = v;
  }
  __syncthreads();
  unsigned short* dst = Vt + ((size_t)b * D_ + d0) * 2048 + t0;
  #pragma unroll
  for (int j = 0; j < 4; ++j) {
    int dd = rr + j * 16;
    int tt = l16 * 4;
    ushort4 v;
    v.x = tile[tt + 0][dd]; v.y = tile[tt + 1][dd];
    v.z = tile[tt + 2][dd]; v.w = tile[tt + 3][dd];
    *(ushort4*)(dst + (size_t)dd * 2048 + tt) = v;
  }
}

// ---------------- 8-phase pipelined GEMM, BK=32, FM=4 ---------------
// (validated engine — QKV 859 TF @3/CU, scores 554 TF @2/CU)
// EPI: 1 = fp16 row-major store; 2 = fp16 store + fused colsum of
//      exp(s-64) via shfl reduce + atomicAdd into CS (scores pass).
template <int EPI>
__global__ __launch_bounds__(512, 4) void gemm8p(
    const unsigned short* __restrict__ A, const unsigned short* __restrict__ B,
    void* __restrict__ C0, float* __restrict__ CS,
    int K, int lda, int ldb, int ldc,
    long aBatch, long bBatch, long cBatch) {
  constexpr int ABY  = 128 * 64;        // 8192 B
  constexpr int BUFB = ABY + 16384;     // 24576 B
  __shared__ __align__(16) char lds[2 * BUFB];

  const int z = blockIdx.z;
  A += (size_t)z * aBatch;
  B += (size_t)z * bBatch;

  const int nwg = gridDim.x * gridDim.y;
  int s = blockIdx.y * gridDim.x + blockIdx.x;
  s = (s & 7) * (nwg >> 3) + (s >> 3);
  const int bx = s % gridDim.x, by = s / gridDim.x;
  const int brow = by * 128, bcol = bx * 256;

  const int tid = threadIdx.x;
  const int wid = tid >> 6, lane = tid & 63;
  const int wr = wid >> 2, wc = wid & 3;
  const int l15 = lane & 15, g4 = lane >> 4;

  const int scol = ((lane & 3) ^ ((lane >> 3) & 3)) * 8;
  const int srow = lane >> 2;
  int aoff, adst, boffs[2], bdst[2];
  {
    int r0 = wid * 16;  // whole A staged as one unit (phase 4 only)
    aoff = (brow + r0 + srow) * lda + scol;
    adst = r0 * 64;
    #pragma unroll
    for (int rg = 0; rg < 2; ++rg) {
      int rb = (wid >> 1) * 64 + rg * 32 + (wid & 1) * 16;  // B-nh{rg} union
      boffs[rg] = (bcol + rb + srow) * ldb + scol;
      bdst[rg]  = ABY + rb * 64;
    }
  }

  const int rslot = (g4 ^ ((l15 >> 1) & 3)) * 16;
  int aRd[2], bRd[2];
  #pragma unroll
  for (int mh = 0; mh < 2; ++mh) {
    aRd[mh] = (wr * 64 + mh * 32 + l15) * 64 + rslot;
    bRd[mh] = ABY + (wc * 64 + mh * 32 + l15) * 64 + rslot;
  }

#define STAGE_A(bb, tt) \
    GLD(A + (size_t)(aoff + (tt) * 32), lds + (bb) * BUFB + adst)
#define STAGE_B(nh, bb, tt) \
    GLD(B + (size_t)(boffs[nh] + (tt) * 32), lds + (bb) * BUFB + bdst[nh])
#define LOAD_A(mh) do { _Pragma("unroll")                                     \
    for (int mf = 0; mf < 2; ++mf)                                            \
      ar[mf] = *(const half8*)(buf + aRd[mh] + mf * 1024); } while (0)
#define LOAD_B(dst, nh) do { _Pragma("unroll")                                \
    for (int nf = 0; nf < 2; ++nf)                                            \
      dst[nf] = *(const half8*)(buf + bRd[nh] + nf * 1024); } while (0)
#define MFMA_Q(mh, nh, br) do { _Pragma("unroll")                             \
    for (int mf = 0; mf < 2; ++mf) { _Pragma("unroll")                        \
      for (int nf = 0; nf < 2; ++nf) {                                        \
        f32x4& ac = acc[(mh) * 2 + mf][(nh) * 2 + nf];                        \
        ac = __builtin_amdgcn_mfma_f32_16x16x32_f16(ar[mf], br[nf], ac, 0, 0, 0); \
      } } } while (0)

  // prologue: stage K-tiles 0 and 1
  STAGE_A(0, 0); STAGE_B(0, 0, 0); STAGE_B(1, 0, 0);
  STAGE_A(1, 1); STAGE_B(0, 1, 1); STAGE_B(1, 1, 1);
  VMW(3);  // buf0 complete
  BAR();

  f32x4 acc[4][4] = {};
  half8 ar[2], b0r[2], b1r[2];
  const int nIter = K / 64;

  for (int it = 0; it < nIter; ++it) {
    const bool st = (it + 1 < nIter);
    #pragma unroll
    for (int h = 0; h < 2; ++h) {
      const char* buf = lds + h * BUFB;
      const int tt = 2 * it + 2 + h;
      LOAD_A(0); LOAD_B(b0r, 0);
      BAR(); LGKM0();
      __builtin_amdgcn_s_setprio(1); MFMA_Q(0, 0, b0r);
      __builtin_amdgcn_s_setprio(0); BAR();
      LOAD_B(b1r, 1);
      if (st) STAGE_B(0, h, tt);
      BAR(); LGKM0();
      __builtin_amdgcn_s_setprio(1); MFMA_Q(0, 1, b1r);
      __builtin_amdgcn_s_setprio(0); BAR();
      LOAD_A(1);
      if (st) STAGE_B(1, h, tt);
      BAR(); LGKM0();
      __builtin_amdgcn_s_setprio(1); MFMA_Q(1, 1, b1r);
      __builtin_amdgcn_s_setprio(0); BAR();
      if (st) STAGE_A(h, tt);
      BAR();
      __builtin_amdgcn_s_setprio(1); MFMA_Q(1, 0, b0r);
      __builtin_amdgcn_s_setprio(0);
      if (st) { VMW(3); } else { VMW(0); }
      BAR();
    }
  }

  // epilogue
  if constexpr (EPI == 1) {
    unsigned short* C = (unsigned short*)C0 + (size_t)z * cBatch;
    #pragma unroll
    for (int m = 0; m < 4; ++m) {
      int rowoff = (m >> 1) * 32 + (m & 1) * 16;
      #pragma unroll
      for (int n = 0; n < 4; ++n) {
        int coloff = (n >> 1) * 32 + (n & 1) * 16;
        #pragma unroll
        for (int r = 0; r < 4; ++r) {
          int row = brow + wr * 64 + rowoff + g4 * 4 + r;
          int col = bcol + wc * 64 + coloff + l15;
          C[(size_t)row * ldc + col] = f2h(acc[m][n][r]);
        }
      }
    }
  } else {  // EPI == 2: fp16 store + fused colsum of exp(s-64)
    unsigned short* C = (unsigned short*)C0 + (size_t)z * cBatch;
    float csum[4] = {0.f, 0.f, 0.f, 0.f};
    #pragma unroll
    for (int m = 0; m < 4; ++m) {
      int rowoff = (m >> 1) * 32 + (m & 1) * 16;
      #pragma unroll
      for (int n = 0; n < 4; ++n) {
        int coloff = (n >> 1) * 32 + (n & 1) * 16;
        #pragma unroll
        for (int r = 0; r < 4; ++r) {
          int row = brow + wr * 64 + rowoff + g4 * 4 + r;
          int col = bcol + wc * 64 + coloff + l15;
          unsigned short hh = f2h(acc[m][n][r]);
          C[(size_t)row * ldc + col] = hh;
          csum[n] += __expf(h2f(hh) - 64.0f);  // exact match with PV weights
        }
      }
    }
    #pragma unroll
    for (int n = 0; n < 4; ++n) {
      csum[n] += __shfl_xor(csum[n], 16);
      csum[n] += __shfl_xor(csum[n], 32);
    }
    if (g4 == 0) {
      #pragma unroll
      for (int n = 0; n < 4; ++n) {
        int col = bcol + wc * 64 + (n >> 1) * 32 + (n & 1) * 16 + l15;
        unsafeAtomicAdd(CS + (size_t)z * T_ + col, csum[n]);
      }
    }
  }
#undef STAGE_A
#undef STAGE_B
#undef LOAD_A
#undef LOAD_B
#undef MFMA_Q
}

// ---------------- PV GEMM, transposed orientation -------------------
// Computes acc = Vt-rows x W-cols (d x q), stores out[q][d] via LDS
// transpose.  A = Vt (64 d-rows, LDS 3-buf/1-bar rotation, 12 KB).
// B = W[q][k] = exp(s-64)*u — loaded DIRECTLY from global in MFMA
// fragment layout (lane: q-row l&15, k-chunk (l>>4)*8) into ping-pong
// register sets, exp'd in-register: NO LDS round-trip for W at all.
// 4 waves, wave-private 64-q panels.  Grid (8,16,4)=512 = 2 blocks/CU.
// vmcnt ledger: 7 issues/tile (1 Vt-GLD + 4 W-frag + 2 u); steady
// VMW(7) drains exactly the previous tile's 7 (count-robust to
// intra-tile reorder); tails VMW(6) @NT-2, VMW(0) @NT-1; prologue
// VMW(0).
__global__ __launch_bounds__(256, 2) void gemmPVt(
    const unsigned short* __restrict__ Sc, const float* __restrict__ U,
    const unsigned short* __restrict__ Vt, float* __restrict__ out) {
  constexpr int BUFB = 4096;                 // 64 rows x 64 B
  __shared__ __align__(16) char lds[34816];  // 3 bufs; epilogue [128][68] f32

  const int b = blockIdx.z;
  Sc += (size_t)b * T_ * T_;
  U  += (size_t)b * T_;
  Vt += (size_t)b * D_ * T_;
  float* Co = out + (size_t)b * T_ * D_;

  const int nwg = gridDim.x * gridDim.y;  // 128
  int s = blockIdx.y * gridDim.x + blockIdx.x;
  s = (s & 7) * (nwg >> 3) + (s >> 3);
  const int bx = s % gridDim.x, by = s / gridDim.x;
  const int q0 = bx * 256, d0 = by * 64;

  const int tid = threadIdx.x;
  const int wid = tid >> 6, lane = tid & 63;
  const int l15 = lane & 15, g4 = lane >> 4;

  // A (Vt) staging: 1 GLD per wave per tile (rows wid*16..+16)
  const int scol = ((lane & 3) ^ ((lane >> 3) & 3)) * 8;
  const int aoff = (d0 + wid * 16 + (lane >> 2)) * T_ + scol;
  const int adst = wid * 1024;

  // A frag reads (swizzled, all 64 rows shared by all waves)
  const int rslot = (g4 ^ ((l15 >> 1) & 3)) * 16;
  int aRd[4];
  #pragma unroll
  for (int mf = 0; mf < 4; ++mf)
    aRd[mf] = (mf * 16 + l15) * 64 + rslot;

  // B (W) direct fragment-layout sources: wave-private q-panel
  const unsigned short* bSrc[4];
  #pragma unroll
  for (int nf = 0; nf < 4; ++nf)
    bSrc[nf] = Sc + (size_t)(q0 + wid * 64 + nf * 16 + l15) * T_ + g4 * 8;
  const float* uSrc = U + g4 * 8;

#define PV_CONV(bw, rW, uA, uB) do {                                          \
    float uu[8] = {uA.x, uA.y, uA.z, uA.w, uB.x, uB.y, uB.z, uB.w};           \
    _Pragma("unroll") for (int nf = 0; nf < 4; ++nf) {                        \
      const unsigned short* hp = (const unsigned short*)&rW[nf];              \
      unsigned int w_[4];                                                     \
      _Pragma("unroll") for (int j = 0; j < 4; ++j) {                         \
        float w0 = __expf(h2f(hp[2 * j])     - 64.f) * uu[2 * j];             \
        float w1 = __expf(h2f(hp[2 * j + 1]) - 64.f) * uu[2 * j + 1];         \
        w_[j] = (unsigned int)f2h(w0) | ((unsigned int)f2h(w1) << 16); }      \
      bw[nf] = *(half8*)w_; } } while (0)

#define PV_TILE(t, rWC, uaC, ubC, rWN, uaN, ubN) do {                         \
    BARM();                                                                   \
    if ((t) + 2 < NT)                                                         \
      GLD(Vt + (size_t)(aoff + ((t) + 2) * 32), bufC + adst);                 \
    if ((t) + 1 < NT) {                                                       \
      _Pragma("unroll") for (int nf = 0; nf < 4; ++nf)                        \
        rWN[nf] = *(const uint4*)(bSrc[nf] + ((t) + 1) * 32);                 \
      uaN = *(const float4*)(uSrc + ((t) + 1) * 32);                          \
      ubN = *(const float4*)(uSrc + ((t) + 1) * 32 + 4);                      \
    }                                                                         \
    if ((t) + 2 < NT)      VMW(7);                                            \
    else if ((t) + 1 < NT) VMW(6);                                            \
    else                   VMW(0);                                            \
    half8 bw[4];                                                              \
    PV_CONV(bw, rWC, uaC, ubC);                                               \
    half8 ar_[4];                                                             \
    _Pragma("unroll") for (int mf = 0; mf < 4; ++mf)                          \
      ar_[mf] = *(const half8*)(bufA + aRd[mf]);                              \
    LGKM0();                                                                  \
    __builtin_amdgcn_s_setprio(1);                                            \
    _Pragma("unroll") for (int mf = 0; mf < 4; ++mf)                          \
      _Pragma("unroll") for (int nf = 0; nf < 4; ++nf)                        \
        acc[mf][nf] = __builtin_amdgcn_mfma_f32_16x16x32_f16(                 \
            ar_[mf], bw[nf], acc[mf][nf], 0, 0, 0);                           \
    __builtin_amdgcn_s_setprio(0);                                            \
    { char* tmp = bufA; bufA = bufB; bufB = bufC; bufC = tmp; } } while (0)

  char* bufA = lds;
  char* bufB = lds + BUFB;
  char* bufC = lds + 2 * BUFB;

  uint4 rW_E[4], rW_O[4];
  float4 uA_E, uB_E, uA_O, uB_O;

  // ---- prologue: Vt(0), Vt(1), W(0) -> E set; drain all ----
  GLD(Vt + (size_t)aoff, bufA + adst);
  GLD(Vt + (size_t)(aoff + 32), bufB + adst);
  #pragma unroll
  for (int nf = 0; nf < 4; ++nf) rW_E[nf] = *(const uint4*)(bSrc[nf]);
  uA_E = *(const float4*)uSrc;
  uB_E = *(const float4*)(uSrc + 4);
  VMW(0);

  f32x4 acc[4][4] = {};
  const int NT = T_ / 32;  // 64 (even)

  for (int t = 0; t < NT; t += 2) {
    PV_TILE(t,     rW_E, uA_E, uB_E, rW_O, uA_O, uB_O);  // even: consume E
    PV_TILE(t + 1, rW_O, uA_O, uB_O, rW_E, uA_E, uB_E);  // odd : consume O
  }

  // ---- epilogue: transpose acc (d x q) -> out[q][d] via LDS ----
  float* T0 = (float*)lds;  // [128][68] fp32
  #pragma unroll
  for (int h = 0; h < 2; ++h) {
    BARM();
    if ((wid >> 1) == h) {
      int qloc = (wid & 1) * 64;
      #pragma unroll
      for (int mf = 0; mf < 4; ++mf)
        #pragma unroll
        for (int nf = 0; nf < 4; ++nf)
          *(f32x4*)&T0[(qloc + nf * 16 + l15) * 68 + mf * 16 + g4 * 4] =
              acc[mf][nf];
    }
    BARM();
    #pragma unroll
    for (int p = 0; p < 8; ++p) {
      int qloc = p * 16 + (tid >> 4);
      int dloc = (tid & 15) * 4;
      f32x4 v = *(const f32x4*)&T0[qloc * 68 + dloc];
      *(f32x4*)&Co[(size_t)(q0 + h * 128 + qloc) * D_ + d0 + dloc] = v;
    }
  }
#undef PV_CONV
#undef PV_TILE
}

// ------- invert column sums ----------------------------------------
__global__ __launch_bounds__(256) void sm_stats(const float* __restrict__ cs,
                                                float* __restrict__ stats) {
  int i = blockIdx.x * 256 + threadIdx.x;  // b*2048 + k
  stats[i] = 1.0f / cs[i];
}

// --------------------------------------------------------------------
extern "C" void kernel_launch(void* const* d_in, const int* in_sizes, int n_in,
                              void* d_out, int out_size, void* d_ws, size_t ws_size,
                              hipStream_t stream) {
  const float* x  = (const float*)d_in[0];
  const float* Wq = (const float*)d_in[1];
  const float* Wk = (const float*)d_in[2];
  const float* Wv = (const float*)d_in[3];
  float* out = (float*)d_out;

  char* ws = (char*)d_ws;
  const size_t MB = 1024ull * 1024ull;
  unsigned short* scoresh = (unsigned short*)(ws);             // 32 MB fp16
  unsigned short* QKVh = (unsigned short*)(ws + 32 * MB);      // 48 MB [8192][3072]
  unsigned short* Vt   = (unsigned short*)(ws + 80 * MB);      // 16 MB [4][1024][2048]
  unsigned short* xh   = (unsigned short*)(ws + 96 * MB);      // 16 MB fp16 x
  unsigned short* Wt   = (unsigned short*)(ws + 112 * MB);     // 6 MB  [3072][1024]
  float* colsum = (float*)(ws + 118 * MB);                     // 32 KB [4][2048]
  float* stats  = (float*)(ws + 118 * MB + 64 * 1024);         // 32 KB fp32 u

  // 1. x -> fp16 (+ zero colsum)
  tofp16_kernel<<<MTOK * D_ / 4 / 256, 256, 0, stream>>>(
      (const float4*)x, (ushort4*)xh, MTOK * D_ / 4,
      (float4*)colsum, B_ * T_ / 4);

  // 2. transpose + concat W -> fp16
  wcat_t_kernel<<<dim3(32, 32, 3), 256, 0, stream>>>(Wq, Wk, Wv, Wt);

  // 3. fused QKV projection (768 blocks -> 3 blocks/CU, 859 TF)
  gemm8p<1><<<dim3(3072 / 256, MTOK / 128, 1), 512, 0, stream>>>(
      xh, Wt, QKVh, nullptr, D_, D_, D_, 3072, 0, 0, 0);

  // 4. V transpose -> Vt[b][d][t]
  vtrans_kernel<<<dim3(T_ / 64, D_ / 64, B_), 256, 0, stream>>>(QKVh, Vt);

  // 5. scores = Q K^T, fp16 + fused colsum (validated r12 engine)
  gemm8p<2><<<dim3(T_ / 256, T_ / 128, B_), 512, 0, stream>>>(
      QKVh, QKVh + 1024, scoresh, colsum, D_, 3072, 3072, T_,
      (long)T_ * 3072, (long)T_ * 3072, (long)T_ * T_);

  // 6. u = 1/colsum
  sm_stats<<<B_ * T_ / 256, 256, 0, stream>>>(colsum, stats);

  // 7. out = exp(S-64)*u @ V — W never touches LDS (reg-fragment path)
  gemmPVt<<<dim3(T_ / 256, D_ / 64, B_), 256, 0, stream>>>(
      scoresh, stats, Vt, out);
}

// Round 15
// 198.238 us; speedup vs baseline: 1.2118x; 1.2118x over previous
//
#include <hip/hip_runtime.h>

#define B_   4
#define T_   2048
#define D_   1024
#define MTOK 8192  // B_*T_

typedef __attribute__((ext_vector_type(8))) _Float16 half8;
typedef __attribute__((ext_vector_type(4))) float    f32x4;

#define GLD(G, L) __builtin_amdgcn_global_load_lds(                       \
    (const __attribute__((address_space(1))) void*)(G),                   \
    (__attribute__((address_space(3))) void*)(L), 16, 0, 0)

#define BAR()   __builtin_amdgcn_s_barrier()
#define BARM()  asm volatile("s_barrier" ::: "memory")
#define LGKM0() do { asm volatile("s_waitcnt lgkmcnt(0)" ::: "memory");   \
                     __builtin_amdgcn_sched_barrier(0); } while (0)
#define VMW(n)  asm volatile("s_waitcnt vmcnt(" #n ")" ::: "memory")

__device__ __forceinline__ unsigned short f2h(float f) {
  return __builtin_bit_cast(unsigned short, (_Float16)f);  // RTE
}
__device__ __forceinline__ float h2f(unsigned short u) {
  return (float)__builtin_bit_cast(_Float16, u);
}

// ---------------- prep: x fp32 -> fp16 (+ zero colsum) --------------
__global__ __launch_bounds__(256) void tofp16_kernel(
    const float4* __restrict__ in, ushort4* __restrict__ out, int n4,
    float4* __restrict__ cs, int c4) {
  int i = blockIdx.x * 256 + threadIdx.x;
  if (i < c4) cs[i] = (float4){0.f, 0.f, 0.f, 0.f};
  if (i >= n4) return;
  float4 v = in[i];
  ushort4 h;
  h.x = f2h(v.x); h.y = f2h(v.y); h.z = f2h(v.z); h.w = f2h(v.w);
  out[i] = h;
}

// ---------------- prep: transpose + concat W -> fp16 ----------------
__global__ __launch_bounds__(256) void wcat_t_kernel(
    const float* __restrict__ Wq, const float* __restrict__ Wk,
    const float* __restrict__ Wv, unsigned short* __restrict__ Wt) {
  __shared__ float tile[32][33];
  int z = blockIdx.z;
  const float* W = (z == 0) ? Wq : ((z == 1) ? Wk : Wv);
  int c0 = blockIdx.x * 32, r0 = blockIdx.y * 32;
  int tx = threadIdx.x & 31, ty = threadIdx.x >> 5;  // 32 x 8
  #pragma unroll
  for (int i = 0; i < 4; ++i)
    tile[ty + i * 8][tx] = W[(size_t)(r0 + ty + i * 8) * D_ + c0 + tx];
  __syncthreads();
  #pragma unroll
  for (int i = 0; i < 4; ++i) {
    float v = tile[tx][ty + i * 8];
    size_t row = (size_t)z * D_ + c0 + ty + i * 8;
    Wt[row * D_ + r0 + tx] = f2h(v);
  }
}

// ---------------- V transpose: QKV cols [2048,3072) -> Vt[b][d][t] --
__global__ __launch_bounds__(256) void vtrans_kernel(
    const unsigned short* __restrict__ QKV, unsigned short* __restrict__ Vt) {
  __shared__ unsigned short tile[64][68];
  int b = blockIdx.z;
  int t0 = blockIdx.x * 64, d0 = blockIdx.y * 64;
  int l16 = threadIdx.x & 15, rr = threadIdx.x >> 4;
  const unsigned short* src =
      QKV + ((size_t)b * 2048 + t0 + rr) * 3072 + 2048 + d0 + l16 * 4;
  #pragma unroll
  for (int i = 0; i < 4; ++i) {
    ushort4 v = *(const ushort4*)(src + (size_t)i * 16 * 3072);
    *(ushort4*)&tile[rr + i * 16][l16 * 4] = v;
  }
  __syncthreads();
  unsigned short* dst = Vt + ((size_t)b * D_ + d0) * 2048 + t0;
  #pragma unroll
  for (int j = 0; j < 4; ++j) {
    int dd = rr + j * 16;
    int tt = l16 * 4;
    ushort4 v;
    v.x = tile[tt + 0][dd]; v.y = tile[tt + 1][dd];
    v.z = tile[tt + 2][dd]; v.w = tile[tt + 3][dd];
    *(ushort4*)(dst + (size_t)dd * 2048 + tt) = v;
  }
}

// ---------------- 8-phase pipelined GEMM, BK=32, FM=4 ---------------
// C[m][n] = sum_k A[m][k]*B[n][k].  BM=128, BN=256, BK=32, 512 thr =
// 8 waves (2M x 4N).  LDS 48 KB (2 buf).
// EPI: 1 = fp16 row-major store; 2 = fp16 store + fused column-sum of
//      exp(s-64) via shfl reduce + atomicAdd into CS (scores pass).
template <int EPI>
__global__ __launch_bounds__(512, 4) void gemm8p(
    const unsigned short* __restrict__ A, const unsigned short* __restrict__ B,
    void* __restrict__ C0, float* __restrict__ CS,
    int K, int lda, int ldb, int ldc,
    long aBatch, long bBatch, long cBatch) {
  constexpr int ABY  = 128 * 64;        // 8192 B
  constexpr int BUFB = ABY + 16384;     // 24576 B
  __shared__ __align__(16) char lds[2 * BUFB];

  const int z = blockIdx.z;
  A += (size_t)z * aBatch;
  B += (size_t)z * bBatch;

  const int nwg = gridDim.x * gridDim.y;
  int s = blockIdx.y * gridDim.x + blockIdx.x;
  s = (s & 7) * (nwg >> 3) + (s >> 3);
  const int bx = s % gridDim.x, by = s / gridDim.x;
  const int brow = by * 128, bcol = bx * 256;

  const int tid = threadIdx.x;
  const int wid = tid >> 6, lane = tid & 63;
  const int wr = wid >> 2, wc = wid & 3;
  const int l15 = lane & 15, g4 = lane >> 4;

  const int scol = ((lane & 3) ^ ((lane >> 3) & 3)) * 8;
  const int srow = lane >> 2;
  int aoff, adst, boffs[2], bdst[2];
  {
    int r0 = wid * 16;  // whole A staged as one unit (phase 4 only)
    aoff = (brow + r0 + srow) * lda + scol;
    adst = r0 * 64;
    #pragma unroll
    for (int rg = 0; rg < 2; ++rg) {
      int rb = (wid >> 1) * 64 + rg * 32 + (wid & 1) * 16;  // B-nh{rg} union
      boffs[rg] = (bcol + rb + srow) * ldb + scol;
      bdst[rg]  = ABY + rb * 64;
    }
  }

  const int rslot = (g4 ^ ((l15 >> 1) & 3)) * 16;
  int aRd[2], bRd[2];
  #pragma unroll
  for (int mh = 0; mh < 2; ++mh) {
    aRd[mh] = (wr * 64 + mh * 32 + l15) * 64 + rslot;
    bRd[mh] = ABY + (wc * 64 + mh * 32 + l15) * 64 + rslot;
  }

#define STAGE_A(bb, tt) \
    GLD(A + (size_t)(aoff + (tt) * 32), lds + (bb) * BUFB + adst)
#define STAGE_B(nh, bb, tt) \
    GLD(B + (size_t)(boffs[nh] + (tt) * 32), lds + (bb) * BUFB + bdst[nh])
#define LOAD_A(mh) do { _Pragma("unroll")                                     \
    for (int mf = 0; mf < 2; ++mf)                                            \
      ar[mf] = *(const half8*)(buf + aRd[mh] + mf * 1024); } while (0)
#define LOAD_B(dst, nh) do { _Pragma("unroll")                                \
    for (int nf = 0; nf < 2; ++nf)                                            \
      dst[nf] = *(const half8*)(buf + bRd[nh] + nf * 1024); } while (0)
#define MFMA_Q(mh, nh, br) do { _Pragma("unroll")                             \
    for (int mf = 0; mf < 2; ++mf) { _Pragma("unroll")                        \
      for (int nf = 0; nf < 2; ++nf) {                                        \
        f32x4& ac = acc[(mh) * 2 + mf][(nh) * 2 + nf];                        \
        ac = __builtin_amdgcn_mfma_f32_16x16x32_f16(ar[mf], br[nf], ac, 0, 0, 0); \
      } } } while (0)

  // prologue: stage K-tiles 0 and 1
  STAGE_A(0, 0); STAGE_B(0, 0, 0); STAGE_B(1, 0, 0);
  STAGE_A(1, 1); STAGE_B(0, 1, 1); STAGE_B(1, 1, 1);
  VMW(3);  // buf0 complete
  BAR();

  f32x4 acc[4][4] = {};
  half8 ar[2], b0r[2], b1r[2];
  const int nIter = K / 64;

  for (int it = 0; it < nIter; ++it) {
    const bool st = (it + 1 < nIter);
    #pragma unroll
    for (int h = 0; h < 2; ++h) {
      const char* buf = lds + h * BUFB;
      const int tt = 2 * it + 2 + h;
      // phase 1: read A-mh0 + B-nh0
      LOAD_A(0); LOAD_B(b0r, 0);
      BAR(); LGKM0();
      __builtin_amdgcn_s_setprio(1); MFMA_Q(0, 0, b0r);
      __builtin_amdgcn_s_setprio(0); BAR();
      // phase 2: read B-nh1; restage B-nh0
      LOAD_B(b1r, 1);
      if (st) STAGE_B(0, h, tt);
      BAR(); LGKM0();
      __builtin_amdgcn_s_setprio(1); MFMA_Q(0, 1, b1r);
      __builtin_amdgcn_s_setprio(0); BAR();
      // phase 3: read A-mh1; restage B-nh1
      LOAD_A(1);
      if (st) STAGE_B(1, h, tt);
      BAR(); LGKM0();
      __builtin_amdgcn_s_setprio(1); MFMA_Q(1, 1, b1r);
      __builtin_amdgcn_s_setprio(0); BAR();
      // phase 4: restage whole A (freed after phase 3)
      if (st) STAGE_A(h, tt);
      BAR();
      __builtin_amdgcn_s_setprio(1); MFMA_Q(1, 0, b0r);
      __builtin_amdgcn_s_setprio(0);
      if (st) { VMW(3); } else { VMW(0); }
      BAR();
    }
  }

  // epilogue
  if constexpr (EPI == 1) {
    unsigned short* C = (unsigned short*)C0 + (size_t)z * cBatch;
    #pragma unroll
    for (int m = 0; m < 4; ++m) {
      int rowoff = (m >> 1) * 32 + (m & 1) * 16;
      #pragma unroll
      for (int n = 0; n < 4; ++n) {
        int coloff = (n >> 1) * 32 + (n & 1) * 16;
        #pragma unroll
        for (int r = 0; r < 4; ++r) {
          int row = brow + wr * 64 + rowoff + g4 * 4 + r;
          int col = bcol + wc * 64 + coloff + l15;
          C[(size_t)row * ldc + col] = f2h(acc[m][n][r]);
        }
      }
    }
  } else {  // EPI == 2: fp16 store + fused colsum of exp(s-64)
    unsigned short* C = (unsigned short*)C0 + (size_t)z * cBatch;
    float csum[4] = {0.f, 0.f, 0.f, 0.f};
    #pragma unroll
    for (int m = 0; m < 4; ++m) {
      int rowoff = (m >> 1) * 32 + (m & 1) * 16;
      #pragma unroll
      for (int n = 0; n < 4; ++n) {
        int coloff = (n >> 1) * 32 + (n & 1) * 16;
        #pragma unroll
        for (int r = 0; r < 4; ++r) {
          int row = brow + wr * 64 + rowoff + g4 * 4 + r;
          int col = bcol + wc * 64 + coloff + l15;
          unsigned short hh = f2h(acc[m][n][r]);
          C[(size_t)row * ldc + col] = hh;
          csum[n] += __expf(h2f(hh) - 64.0f);  // exact match with PV weights
        }
      }
    }
    #pragma unroll
    for (int n = 0; n < 4; ++n) {
      csum[n] += __shfl_xor(csum[n], 16);
      csum[n] += __shfl_xor(csum[n], 32);
    }
    if (g4 == 0) {
      #pragma unroll
      for (int n = 0; n < 4; ++n) {
        int col = bcol + wc * 64 + (n >> 1) * 32 + (n & 1) * 16 + l15;
        unsafeAtomicAdd(CS + (size_t)z * T_ + col, csum[n]);
      }
    }
  }
#undef STAGE_A
#undef STAGE_B
#undef LOAD_A
#undef LOAD_B
#undef MFMA_Q
}

// ---------------- PV GEMM: BM=64/BN=256, 4 waves, 3-buf 1-bar -------
// out[q][d] = sum_k w[q][k]*Vt[d][k], w = exp(s-64)*u[k] fused into the
// reg-staged A path.  256 thr = 4 waves, each wave owns a 64x64 panel
// (8 ds_reads / 16 MFMA).  Grid (4,32,4) = 512 blocks = 2 blocks/CU.
// 3 buffers: stage->buf[t+2], read->buf[t]; single tile-top barrier
// orders write-after-read.  vmcnt ledger (7 issues/tile): steady VMW(4)
// after MFMA drains B(t+1)x4 + A(t+2)-regs, leaves B(t+2)x4; prologue
// VMW(11)->VMW(4); tail VMW(0) at t==NT-2.
__global__ __launch_bounds__(256, 2) void gemmPV(
    const unsigned short* __restrict__ Sc, const float* __restrict__ U,
    const unsigned short* __restrict__ Bv, float* __restrict__ out) {
  constexpr int ABY  = 64 * 64;       // 4096 B
  constexpr int BUFB = ABY + 16384;   // 20480 B per buffer
  __shared__ __align__(16) char lds[3 * BUFB];

  const int b = blockIdx.z;
  Sc += (size_t)b * T_ * T_;
  U  += (size_t)b * T_;
  Bv += (size_t)b * D_ * T_;
  float* Co = out + (size_t)b * T_ * D_;

  const int nwg = gridDim.x * gridDim.y;  // 128, %8==0
  int s = blockIdx.y * gridDim.x + blockIdx.x;
  s = (s & 7) * (nwg >> 3) + (s >> 3);
  const int bx = s % gridDim.x, by = s / gridDim.x;
  const int brow = by * 64, bcol = bx * 256;

  const int tid = threadIdx.x;
  const int wid = tid >> 6, lane = tid & 63;
  const int l15 = lane & 15, g4 = lane >> 4;

  // A staging (fused exp): thread -> (row tid>>2, slot tid&3); one 16B
  // swizzled ds_write each.  key = (row>>1)&3 = (tid>>3)&3.
  const int arow = tid >> 2;
  const unsigned short* aSrc = Sc + (size_t)(brow + arow) * T_ + (tid & 3) * 8;
  const int awB  = arow * 64 + ((tid & 3) ^ ((tid >> 3) & 3)) * 16;
  const int ucol = (tid & 3) * 8;

  // B staging: 4 GLDs per wave (inverse-swizzled global source)
  const int scol = ((lane & 3) ^ ((lane >> 3) & 3)) * 8;
  const int srow = lane >> 2;
  int boffs[4], bdst[4];
  #pragma unroll
  for (int g = 0; g < 4; ++g) {
    int rb = g * 64 + wid * 16;
    boffs[g] = (bcol + rb + srow) * T_ + scol;
    bdst[g]  = ABY + rb * 64;
  }

  // read geometry (swizzled ds_read_b128)
  const int rslot = (g4 ^ ((l15 >> 1) & 3)) * 16;
  int aRd[4], bRd[4];
  #pragma unroll
  for (int mf = 0; mf < 4; ++mf)
    aRd[mf] = (mf * 16 + l15) * 64 + rslot;
  #pragma unroll
  for (int nf = 0; nf < 4; ++nf)
    bRd[nf] = ABY + (wid * 64 + nf * 16 + l15) * 64 + rslot;

  uint4 rawA;
  float4 uva, uvb;

#define PV_BSTAGE(base, tt) do { _Pragma("unroll")                            \
    for (int g = 0; g < 4; ++g)                                               \
      GLD(Bv + (size_t)(boffs[g] + (tt) * 32), (base) + bdst[g]); } while (0)
#define PV_AISSUE(tt) do {                                                    \
    rawA = *(const uint4*)(aSrc + (size_t)(tt) * 32);                         \
    uva  = *(const float4*)(U + (tt) * 32 + ucol);                            \
    uvb  = *(const float4*)(U + (tt) * 32 + ucol + 4); } while (0)
#define PV_AWRITE(base) do {                                                  \
    const unsigned short* hp = (const unsigned short*)&rawA;                  \
    float uu[8] = {uva.x, uva.y, uva.z, uva.w, uvb.x, uvb.y, uvb.z, uvb.w};   \
    unsigned int w_[4];                                                       \
    _Pragma("unroll") for (int j = 0; j < 4; ++j) {                           \
      float w0 = __expf(h2f(hp[2 * j])     - 64.f) * uu[2 * j];               \
      float w1 = __expf(h2f(hp[2 * j + 1]) - 64.f) * uu[2 * j + 1];           \
      w_[j] = (unsigned int)f2h(w0) | ((unsigned int)f2h(w1) << 16); }        \
    *(uint4*)((base) + awB) = *(uint4*)w_; } while (0)

  char* bufA = lds;              // tile t
  char* bufB = lds + BUFB;       // tile t+1
  char* bufC = lds + 2 * BUFB;   // tile t+2 (stage target)

  // ---- prologue: tiles 0 (bufA) and 1 (bufB); 14 vmem issues ----
  PV_AISSUE(0);                  // 3
  PV_BSTAGE(bufA, 0);            // +4 = 7
  uint4  rawA1 = *(const uint4*)(aSrc + 32);          // +1
  float4 uva1  = *(const float4*)(U + 32 + ucol);     // +1
  float4 uvb1  = *(const float4*)(U + 32 + ucol + 4); // +1 = 10
  PV_BSTAGE(bufB, 1);            // +4 = 14
  VMW(11);  // drain A0,u,u
  PV_AWRITE(bufA);
  VMW(4);   // drain B0 x4 + A1-regs; leaves B1 x4
  rawA = rawA1; uva = uva1; uvb = uvb1;
  PV_AWRITE(bufB);
  asm volatile("s_waitcnt lgkmcnt(0)" ::: "memory");

  f32x4 acc[4][4] = {};
  half8 ar[4], br[4];
  const int NT = T_ / 32;  // 64

  for (int t = 0; t < NT; ++t) {
    BARM();  // publishes buf[t] (B drained at t-1's VMW, A-writes drained)
    const bool st = (t + 2 < NT);
    if (st) {
      PV_AISSUE(t + 2);
      PV_BSTAGE(bufC, t + 2);
    }
    #pragma unroll
    for (int mf = 0; mf < 4; ++mf)
      ar[mf] = *(const half8*)(bufA + aRd[mf]);
    #pragma unroll
    for (int nf = 0; nf < 4; ++nf)
      br[nf] = *(const half8*)(bufA + bRd[nf]);
    __builtin_amdgcn_s_setprio(1);
    #pragma unroll
    for (int mf = 0; mf < 4; ++mf)
      #pragma unroll
      for (int nf = 0; nf < 4; ++nf)
        acc[mf][nf] = __builtin_amdgcn_mfma_f32_16x16x32_f16(ar[mf], br[nf], acc[mf][nf], 0, 0, 0);
    __builtin_amdgcn_s_setprio(0);
    if (st) {
      VMW(4);            // drain B(t+1) x4 + A(t+2)-regs; keep B(t+2) x4
      PV_AWRITE(bufC);
      asm volatile("s_waitcnt lgkmcnt(0)" ::: "memory");
    } else if (t + 2 == NT) {
      VMW(0);            // drain B(NT-1) before its tile
    }
    char* tmp = bufA; bufA = bufB; bufB = bufC; bufC = tmp;
  }

  // epilogue: coalesced fp32 stores
  #pragma unroll
  for (int mf = 0; mf < 4; ++mf)
    #pragma unroll
    for (int nf = 0; nf < 4; ++nf)
      #pragma unroll
      for (int r = 0; r < 4; ++r) {
        int row = brow + mf * 16 + g4 * 4 + r;
        int col = bcol + wid * 64 + nf * 16 + l15;
        Co[(size_t)row * D_ + col] = acc[mf][nf][r];
      }
#undef PV_BSTAGE
#undef PV_AISSUE
#undef PV_AWRITE
}

// ------- invert column sums ----------------------------------------
__global__ __launch_bounds__(256) void sm_stats(const float* __restrict__ cs,
                                                float* __restrict__ stats) {
  int i = blockIdx.x * 256 + threadIdx.x;  // b*2048 + k
  stats[i] = 1.0f / cs[i];
}

// --------------------------------------------------------------------
extern "C" void kernel_launch(void* const* d_in, const int* in_sizes, int n_in,
                              void* d_out, int out_size, void* d_ws, size_t ws_size,
                              hipStream_t stream) {
  const float* x  = (const float*)d_in[0];
  const float* Wq = (const float*)d_in[1];
  const float* Wk = (const float*)d_in[2];
  const float* Wv = (const float*)d_in[3];
  float* out = (float*)d_out;

  char* ws = (char*)d_ws;
  const size_t MB = 1024ull * 1024ull;
  unsigned short* scoresh = (unsigned short*)(ws);             // 32 MB fp16
  unsigned short* QKVh = (unsigned short*)(ws + 32 * MB);      // 48 MB [8192][3072]
  unsigned short* Vt   = (unsigned short*)(ws + 80 * MB);      // 16 MB [4][1024][2048]
  unsigned short* xh   = (unsigned short*)(ws + 96 * MB);      // 16 MB fp16 x
  unsigned short* Wt   = (unsigned short*)(ws + 112 * MB);     // 6 MB  [3072][1024]
  float* colsum = (float*)(ws + 118 * MB);                     // 32 KB [4][2048]
  float* stats  = (float*)(ws + 118 * MB + 64 * 1024);         // 32 KB fp32 u

  // 1. x -> fp16 (+ zero colsum for the fused-colsum scores pass)
  tofp16_kernel<<<MTOK * D_ / 4 / 256, 256, 0, stream>>>(
      (const float4*)x, (ushort4*)xh, MTOK * D_ / 4,
      (float4*)colsum, B_ * T_ / 4);

  // 2. transpose + concat W -> fp16
  wcat_t_kernel<<<dim3(32, 32, 3), 256, 0, stream>>>(Wq, Wk, Wv, Wt);

  // 3. fused QKV projection (FM=4, 768 blocks -> 3 blocks/CU)
  gemm8p<1><<<dim3(3072 / 256, MTOK / 128, 1), 512, 0, stream>>>(
      xh, Wt, QKVh, nullptr, D_, D_, D_, 3072, 0, 0, 0);

  // 4. V transpose -> Vt[b][d][t]
  vtrans_kernel<<<dim3(T_ / 64, D_ / 64, B_), 256, 0, stream>>>(QKVh, Vt);

  // 5. scores = Q K^T, fp16 out + fused column-sum of exp(s-64)
  gemm8p<2><<<dim3(T_ / 256, T_ / 128, B_), 512, 0, stream>>>(
      QKVh, QKVh + 1024, scoresh, colsum, D_, 3072, 3072, T_,
      (long)T_ * 3072, (long)T_ * 3072, (long)T_ * T_);

  // 6. u = 1/colsum
  sm_stats<<<B_ * T_ / 256, 256, 0, stream>>>(colsum, stats);

  // 7. out = exp(S-64)*u @ V  (BM=64/BN=256, 512 blocks = 2/CU)
  gemmPV<<<dim3(D_ / 256, T_ / 64, B_), 256, 0, stream>>>(
      scoresh, stats, Vt, out);
}

// Round 16
// 194.811 us; speedup vs baseline: 1.2332x; 1.0176x over previous
//
#include <hip/hip_runtime.h>

#define B_   4
#define T_   2048
#define D_   1024
#define MTOK 8192  // B_*T_

typedef __attribute__((ext_vector_type(8))) _Float16 half8;
typedef __attribute__((ext_vector_type(4))) float    f32x4;

#define GLD(G, L) __builtin_amdgcn_global_load_lds(                       \
    (const __attribute__((address_space(1))) void*)(G),                   \
    (__attribute__((address_space(3))) void*)(L), 16, 0, 0)

#define BAR()   __builtin_amdgcn_s_barrier()
#define BARM()  asm volatile("s_barrier" ::: "memory")
#define LGKM0() do { asm volatile("s_waitcnt lgkmcnt(0)" ::: "memory");   \
                     __builtin_amdgcn_sched_barrier(0); } while (0)
#define VMW(n)  asm volatile("s_waitcnt vmcnt(" #n ")" ::: "memory")

__device__ __forceinline__ unsigned short f2h(float f) {
  return __builtin_bit_cast(unsigned short, (_Float16)f);  // RTE
}
__device__ __forceinline__ float h2f(unsigned short u) {
  return (float)__builtin_bit_cast(_Float16, u);
}

// ---------------- prep: x fp32 -> fp16 (+ zero colsum) --------------
__global__ __launch_bounds__(256) void tofp16_kernel(
    const float4* __restrict__ in, ushort4* __restrict__ out, int n4,
    float4* __restrict__ cs, int c4) {
  int i = blockIdx.x * 256 + threadIdx.x;
  if (i < c4) cs[i] = (float4){0.f, 0.f, 0.f, 0.f};
  if (i >= n4) return;
  float4 v = in[i];
  ushort4 h;
  h.x = f2h(v.x); h.y = f2h(v.y); h.z = f2h(v.z); h.w = f2h(v.w);
  out[i] = h;
}

// ---------------- prep: transpose + concat W -> fp16 ----------------
__global__ __launch_bounds__(256) void wcat_t_kernel(
    const float* __restrict__ Wq, const float* __restrict__ Wk,
    const float* __restrict__ Wv, unsigned short* __restrict__ Wt) {
  __shared__ float tile[32][33];
  int z = blockIdx.z;
  const float* W = (z == 0) ? Wq : ((z == 1) ? Wk : Wv);
  int c0 = blockIdx.x * 32, r0 = blockIdx.y * 32;
  int tx = threadIdx.x & 31, ty = threadIdx.x >> 5;  // 32 x 8
  #pragma unroll
  for (int i = 0; i < 4; ++i)
    tile[ty + i * 8][tx] = W[(size_t)(r0 + ty + i * 8) * D_ + c0 + tx];
  __syncthreads();
  #pragma unroll
  for (int i = 0; i < 4; ++i) {
    float v = tile[tx][ty + i * 8];
    size_t row = (size_t)z * D_ + c0 + ty + i * 8;
    Wt[row * D_ + r0 + tx] = f2h(v);
  }
}

// ---------------- 8-phase pipelined GEMM, BK=32, FM=4 ---------------
// C[m][n] = sum_k A[m][k]*B[n][k].  BM=128, BN=256, BK=32, 512 thr =
// 8 waves (2M x 4N).  LDS 48 KB (2 buf).
// EPI: 2 = fp16 store + fused column-sum of exp(s-64) (scores pass);
//      3 = QKV pass: bcol<2048 -> fp16 row-major store to C0 (QK);
//          bcol>=2048 -> LDS-transposed coalesced store to C1 = Vt
//          (replaces the separate vtrans kernel; V bits identical).
template <int EPI>
__global__ __launch_bounds__(512, 4) void gemm8p(
    const unsigned short* __restrict__ A, const unsigned short* __restrict__ B,
    void* __restrict__ C0, void* __restrict__ C1, float* __restrict__ CS,
    int K, int lda, int ldb, int ldc,
    long aBatch, long bBatch, long cBatch) {
  constexpr int ABY  = 128 * 64;        // 8192 B
  constexpr int BUFB = ABY + 16384;     // 24576 B
  __shared__ __align__(16) char lds[2 * BUFB];

  const int z = blockIdx.z;
  A += (size_t)z * aBatch;
  B += (size_t)z * bBatch;

  const int nwg = gridDim.x * gridDim.y;
  int s = blockIdx.y * gridDim.x + blockIdx.x;
  s = (s & 7) * (nwg >> 3) + (s >> 3);
  const int bx = s % gridDim.x, by = s / gridDim.x;
  const int brow = by * 128, bcol = bx * 256;

  const int tid = threadIdx.x;
  const int wid = tid >> 6, lane = tid & 63;
  const int wr = wid >> 2, wc = wid & 3;
  const int l15 = lane & 15, g4 = lane >> 4;

  const int scol = ((lane & 3) ^ ((lane >> 3) & 3)) * 8;
  const int srow = lane >> 2;
  int aoff, adst, boffs[2], bdst[2];
  {
    int r0 = wid * 16;  // whole A staged as one unit (phase 4 only)
    aoff = (brow + r0 + srow) * lda + scol;
    adst = r0 * 64;
    #pragma unroll
    for (int rg = 0; rg < 2; ++rg) {
      int rb = (wid >> 1) * 64 + rg * 32 + (wid & 1) * 16;  // B-nh{rg} union
      boffs[rg] = (bcol + rb + srow) * ldb + scol;
      bdst[rg]  = ABY + rb * 64;
    }
  }

  const int rslot = (g4 ^ ((l15 >> 1) & 3)) * 16;
  int aRd[2], bRd[2];
  #pragma unroll
  for (int mh = 0; mh < 2; ++mh) {
    aRd[mh] = (wr * 64 + mh * 32 + l15) * 64 + rslot;
    bRd[mh] = ABY + (wc * 64 + mh * 32 + l15) * 64 + rslot;
  }

#define STAGE_A(bb, tt) \
    GLD(A + (size_t)(aoff + (tt) * 32), lds + (bb) * BUFB + adst)
#define STAGE_B(nh, bb, tt) \
    GLD(B + (size_t)(boffs[nh] + (tt) * 32), lds + (bb) * BUFB + bdst[nh])
#define LOAD_A(mh) do { _Pragma("unroll")                                     \
    for (int mf = 0; mf < 2; ++mf)                                            \
      ar[mf] = *(const half8*)(buf + aRd[mh] + mf * 1024); } while (0)
#define LOAD_B(dst, nh) do { _Pragma("unroll")                                \
    for (int nf = 0; nf < 2; ++nf)                                            \
      dst[nf] = *(const half8*)(buf + bRd[nh] + nf * 1024); } while (0)
#define MFMA_Q(mh, nh, br) do { _Pragma("unroll")                             \
    for (int mf = 0; mf < 2; ++mf) { _Pragma("unroll")                        \
      for (int nf = 0; nf < 2; ++nf) {                                        \
        f32x4& ac = acc[(mh) * 2 + mf][(nh) * 2 + nf];                        \
        ac = __builtin_amdgcn_mfma_f32_16x16x32_f16(ar[mf], br[nf], ac, 0, 0, 0); \
      } } } while (0)

  // prologue: stage K-tiles 0 and 1
  STAGE_A(0, 0); STAGE_B(0, 0, 0); STAGE_B(1, 0, 0);
  STAGE_A(1, 1); STAGE_B(0, 1, 1); STAGE_B(1, 1, 1);
  VMW(3);  // buf0 complete
  BAR();

  f32x4 acc[4][4] = {};
  half8 ar[2], b0r[2], b1r[2];
  const int nIter = K / 64;

  for (int it = 0; it < nIter; ++it) {
    const bool st = (it + 1 < nIter);
    #pragma unroll
    for (int h = 0; h < 2; ++h) {
      const char* buf = lds + h * BUFB;
      const int tt = 2 * it + 2 + h;
      // phase 1: read A-mh0 + B-nh0
      LOAD_A(0); LOAD_B(b0r, 0);
      BAR(); LGKM0();
      __builtin_amdgcn_s_setprio(1); MFMA_Q(0, 0, b0r);
      __builtin_amdgcn_s_setprio(0); BAR();
      // phase 2: read B-nh1; restage B-nh0
      LOAD_B(b1r, 1);
      if (st) STAGE_B(0, h, tt);
      BAR(); LGKM0();
      __builtin_amdgcn_s_setprio(1); MFMA_Q(0, 1, b1r);
      __builtin_amdgcn_s_setprio(0); BAR();
      // phase 3: read A-mh1; restage B-nh1
      LOAD_A(1);
      if (st) STAGE_B(1, h, tt);
      BAR(); LGKM0();
      __builtin_amdgcn_s_setprio(1); MFMA_Q(1, 1, b1r);
      __builtin_amdgcn_s_setprio(0); BAR();
      // phase 4: restage whole A (freed after phase 3)
      if (st) STAGE_A(h, tt);
      BAR();
      __builtin_amdgcn_s_setprio(1); MFMA_Q(1, 0, b0r);
      __builtin_amdgcn_s_setprio(0);
      if (st) { VMW(3); } else { VMW(0); }
      BAR();
    }
  }

  // epilogue
  if constexpr (EPI == 2) {  // fp16 store + fused colsum of exp(s-64)
    unsigned short* C = (unsigned short*)C0 + (size_t)z * cBatch;
    float csum[4] = {0.f, 0.f, 0.f, 0.f};
    #pragma unroll
    for (int m = 0; m < 4; ++m) {
      int rowoff = (m >> 1) * 32 + (m & 1) * 16;
      #pragma unroll
      for (int n = 0; n < 4; ++n) {
        int coloff = (n >> 1) * 32 + (n & 1) * 16;
        #pragma unroll
        for (int r = 0; r < 4; ++r) {
          int row = brow + wr * 64 + rowoff + g4 * 4 + r;
          int col = bcol + wc * 64 + coloff + l15;
          unsigned short hh = f2h(acc[m][n][r]);
          C[(size_t)row * ldc + col] = hh;
          csum[n] += __expf(h2f(hh) - 64.0f);  // exact match with PV weights
        }
      }
    }
    #pragma unroll
    for (int n = 0; n < 4; ++n) {
      csum[n] += __shfl_xor(csum[n], 16);
      csum[n] += __shfl_xor(csum[n], 32);
    }
    if (g4 == 0) {
      #pragma unroll
      for (int n = 0; n < 4; ++n) {
        int col = bcol + wc * 64 + (n >> 1) * 32 + (n & 1) * 16 + l15;
        unsafeAtomicAdd(CS + (size_t)z * T_ + col, csum[n]);
      }
    }
  } else {  // EPI == 3: QKV pass
    if (bcol < 2048) {
      // QK columns: fp16 row-major store (ldc = 3072)
      unsigned short* C = (unsigned short*)C0;
      #pragma unroll
      for (int m = 0; m < 4; ++m) {
        int rowoff = (m >> 1) * 32 + (m & 1) * 16;
        #pragma unroll
        for (int n = 0; n < 4; ++n) {
          int coloff = (n >> 1) * 32 + (n & 1) * 16;
          #pragma unroll
          for (int r = 0; r < 4; ++r) {
            int row = brow + wr * 64 + rowoff + g4 * 4 + r;
            int col = bcol + wc * 64 + coloff + l15;
            C[(size_t)row * ldc + col] = f2h(acc[m][n][r]);
          }
        }
      }
    } else {
      // V columns: transpose 128(t) x 256(d) acc via LDS -> Vt[b][d][t]
      // (the K-loop's final BAR means all waves are done with lds)
      unsigned short* VT = (unsigned short*)C1;
      const int bq = brow >> 11;        // batch (128 | 2048 -> uniform)
      const int t0 = brow & 2047;
      const int d0 = bcol - 2048;
      unsigned short (*T)[136] = (unsigned short(*)[136])lds;  // 34816 B
      #pragma unroll
      for (int h = 0; h < 2; ++h) {     // d-half: cols [h*128, h*128+128)
        BARM();                         // prior half's reads complete
        if ((wc >> 1) == h) {
          int dbase = (wc & 1) * 64;
          #pragma unroll
          for (int m = 0; m < 4; ++m) {
            int tloc = wr * 64 + (m >> 1) * 32 + (m & 1) * 16 + g4 * 4;
            #pragma unroll
            for (int n = 0; n < 4; ++n) {
              int dloc = dbase + (n >> 1) * 32 + (n & 1) * 16 + l15;
              unsigned short pk[4];
              #pragma unroll
              for (int r = 0; r < 4; ++r) pk[r] = f2h(acc[m][n][r]);
              *(uint2*)&T[dloc][tloc] = *(const uint2*)pk;  // 8 B, aligned
            }
          }
        }
        BARM();                         // half-h tile fully written
        // cooperative coalesced store: 512 thr cover 128 d x 128 t
        int dloc = tid >> 2;
        int tc   = (tid & 3) * 32;
        unsigned short* dst =
            VT + ((size_t)bq * D_ + d0 + h * 128 + dloc) * 2048 + t0 + tc;
        #pragma unroll
        for (int i = 0; i < 4; ++i)
          *(uint4*)(dst + i * 8) = *(const uint4*)&T[dloc][tc + i * 8];
      }
    }
  }
#undef STAGE_A
#undef STAGE_B
#undef LOAD_A
#undef LOAD_B
#undef MFMA_Q
}

// ---------------- PV GEMM: BM=64/BN=256, 4 waves, 3-buf 1-bar -------
// out[q][d] = sum_k w[q][k]*Vt[d][k], w = exp(s-64)*u[k] fused into the
// reg-staged A path.  256 thr = 4 waves, each wave owns a 64x64 panel
// (8 ds_reads / 16 MFMA).  Grid (4,32,4) = 512 blocks = 2 blocks/CU.
// 3 buffers: stage->buf[t+2], read->buf[t]; single tile-top barrier
// orders write-after-read.  vmcnt ledger (7 issues/tile): steady VMW(4)
// after MFMA drains B(t+1)x4 + A(t+2)-regs, leaves B(t+2)x4; prologue
// VMW(11)->VMW(4); tail VMW(0) at t==NT-2.
__global__ __launch_bounds__(256, 2) void gemmPV(
    const unsigned short* __restrict__ Sc, const float* __restrict__ U,
    const unsigned short* __restrict__ Bv, float* __restrict__ out) {
  constexpr int ABY  = 64 * 64;       // 4096 B
  constexpr int BUFB = ABY + 16384;   // 20480 B per buffer
  __shared__ __align__(16) char lds[3 * BUFB];

  const int b = blockIdx.z;
  Sc += (size_t)b * T_ * T_;
  U  += (size_t)b * T_;
  Bv += (size_t)b * D_ * T_;
  float* Co = out + (size_t)b * T_ * D_;

  const int nwg = gridDim.x * gridDim.y;  // 128, %8==0
  int s = blockIdx.y * gridDim.x + blockIdx.x;
  s = (s & 7) * (nwg >> 3) + (s >> 3);
  const int bx = s % gridDim.x, by = s / gridDim.x;
  const int brow = by * 64, bcol = bx * 256;

  const int tid = threadIdx.x;
  const int wid = tid >> 6, lane = tid & 63;
  const int l15 = lane & 15, g4 = lane >> 4;

  // A staging (fused exp): thread -> (row tid>>2, slot tid&3); one 16B
  // swizzled ds_write each.  key = (row>>1)&3 = (tid>>3)&3.
  const int arow = tid >> 2;
  const unsigned short* aSrc = Sc + (size_t)(brow + arow) * T_ + (tid & 3) * 8;
  const int awB  = arow * 64 + ((tid & 3) ^ ((tid >> 3) & 3)) * 16;
  const int ucol = (tid & 3) * 8;

  // B staging: 4 GLDs per wave (inverse-swizzled global source)
  const int scol = ((lane & 3) ^ ((lane >> 3) & 3)) * 8;
  const int srow = lane >> 2;
  int boffs[4], bdst[4];
  #pragma unroll
  for (int g = 0; g < 4; ++g) {
    int rb = g * 64 + wid * 16;
    boffs[g] = (bcol + rb + srow) * T_ + scol;
    bdst[g]  = ABY + rb * 64;
  }

  // read geometry (swizzled ds_read_b128)
  const int rslot = (g4 ^ ((l15 >> 1) & 3)) * 16;
  int aRd[4], bRd[4];
  #pragma unroll
  for (int mf = 0; mf < 4; ++mf)
    aRd[mf] = (mf * 16 + l15) * 64 + rslot;
  #pragma unroll
  for (int nf = 0; nf < 4; ++nf)
    bRd[nf] = ABY + (wid * 64 + nf * 16 + l15) * 64 + rslot;

  uint4 rawA;
  float4 uva, uvb;

#define PV_BSTAGE(base, tt) do { _Pragma("unroll")                            \
    for (int g = 0; g < 4; ++g)                                               \
      GLD(Bv + (size_t)(boffs[g] + (tt) * 32), (base) + bdst[g]); } while (0)
#define PV_AISSUE(tt) do {                                                    \
    rawA = *(const uint4*)(aSrc + (size_t)(tt) * 32);                         \
    uva  = *(const float4*)(U + (tt) * 32 + ucol);                            \
    uvb  = *(const float4*)(U + (tt) * 32 + ucol + 4); } while (0)
#define PV_AWRITE(base) do {                                                  \
    const unsigned short* hp = (const unsigned short*)&rawA;                  \
    float uu[8] = {uva.x, uva.y, uva.z, uva.w, uvb.x, uvb.y, uvb.z, uvb.w};   \
    unsigned int w_[4];                                                       \
    _Pragma("unroll") for (int j = 0; j < 4; ++j) {                           \
      float w0 = __expf(h2f(hp[2 * j])     - 64.f) * uu[2 * j];               \
      float w1 = __expf(h2f(hp[2 * j + 1]) - 64.f) * uu[2 * j + 1];           \
      w_[j] = (unsigned int)f2h(w0) | ((unsigned int)f2h(w1) << 16); }        \
    *(uint4*)((base) + awB) = *(uint4*)w_; } while (0)

  char* bufA = lds;              // tile t
  char* bufB = lds + BUFB;       // tile t+1
  char* bufC = lds + 2 * BUFB;   // tile t+2 (stage target)

  // ---- prologue: tiles 0 (bufA) and 1 (bufB); 14 vmem issues ----
  PV_AISSUE(0);                  // 3
  PV_BSTAGE(bufA, 0);            // +4 = 7
  uint4  rawA1 = *(const uint4*)(aSrc + 32);          // +1
  float4 uva1  = *(const float4*)(U + 32 + ucol);     // +1
  float4 uvb1  = *(const float4*)(U + 32 + ucol + 4); // +1 = 10
  PV_BSTAGE(bufB, 1);            // +4 = 14
  VMW(11);  // drain A0,u,u
  PV_AWRITE(bufA);
  VMW(4);   // drain B0 x4 + A1-regs; leaves B1 x4
  rawA = rawA1; uva = uva1; uvb = uvb1;
  PV_AWRITE(bufB);
  asm volatile("s_waitcnt lgkmcnt(0)" ::: "memory");

  f32x4 acc[4][4] = {};
  half8 ar[4], br[4];
  const int NT = T_ / 32;  // 64

  for (int t = 0; t < NT; ++t) {
    BARM();  // publishes buf[t] (B drained at t-1's VMW, A-writes drained)
    const bool st = (t + 2 < NT);
    if (st) {
      PV_AISSUE(t + 2);
      PV_BSTAGE(bufC, t + 2);
    }
    #pragma unroll
    for (int mf = 0; mf < 4; ++mf)
      ar[mf] = *(const half8*)(bufA + aRd[mf]);
    #pragma unroll
    for (int nf = 0; nf < 4; ++nf)
      br[nf] = *(const half8*)(bufA + bRd[nf]);
    __builtin_amdgcn_s_setprio(1);
    #pragma unroll
    for (int mf = 0; mf < 4; ++mf)
      #pragma unroll
      for (int nf = 0; nf < 4; ++nf)
        acc[mf][nf] = __builtin_amdgcn_mfma_f32_16x16x32_f16(ar[mf], br[nf], acc[mf][nf], 0, 0, 0);
    __builtin_amdgcn_s_setprio(0);
    if (st) {
      VMW(4);            // drain B(t+1) x4 + A(t+2)-regs; keep B(t+2) x4
      PV_AWRITE(bufC);
      asm volatile("s_waitcnt lgkmcnt(0)" ::: "memory");
    } else if (t + 2 == NT) {
      VMW(0);            // drain B(NT-1) before its tile
    }
    char* tmp = bufA; bufA = bufB; bufB = bufC; bufC = tmp;
  }

  // epilogue: coalesced fp32 stores
  #pragma unroll
  for (int mf = 0; mf < 4; ++mf)
    #pragma unroll
    for (int nf = 0; nf < 4; ++nf)
      #pragma unroll
      for (int r = 0; r < 4; ++r) {
        int row = brow + mf * 16 + g4 * 4 + r;
        int col = bcol + wid * 64 + nf * 16 + l15;
        Co[(size_t)row * D_ + col] = acc[mf][nf][r];
      }
#undef PV_BSTAGE
#undef PV_AISSUE
#undef PV_AWRITE
}

// ------- invert column sums ----------------------------------------
__global__ __launch_bounds__(256) void sm_stats(const float* __restrict__ cs,
                                                float* __restrict__ stats) {
  int i = blockIdx.x * 256 + threadIdx.x;  // b*2048 + k
  stats[i] = 1.0f / cs[i];
}

// --------------------------------------------------------------------
extern "C" void kernel_launch(void* const* d_in, const int* in_sizes, int n_in,
                              void* d_out, int out_size, void* d_ws, size_t ws_size,
                              hipStream_t stream) {
  const float* x  = (const float*)d_in[0];
  const float* Wq = (const float*)d_in[1];
  const float* Wk = (const float*)d_in[2];
  const float* Wv = (const float*)d_in[3];
  float* out = (float*)d_out;

  char* ws = (char*)d_ws;
  const size_t MB = 1024ull * 1024ull;
  unsigned short* scoresh = (unsigned short*)(ws);             // 32 MB fp16
  unsigned short* QKVh = (unsigned short*)(ws + 32 * MB);      // 48 MB [8192][3072] (QK thirds used)
  unsigned short* Vt   = (unsigned short*)(ws + 80 * MB);      // 16 MB [4][1024][2048]
  unsigned short* xh   = (unsigned short*)(ws + 96 * MB);      // 16 MB fp16 x
  unsigned short* Wt   = (unsigned short*)(ws + 112 * MB);     // 6 MB  [3072][1024]
  float* colsum = (float*)(ws + 118 * MB);                     // 32 KB [4][2048]
  float* stats  = (float*)(ws + 118 * MB + 64 * 1024);         // 32 KB fp32 u

  // 1. x -> fp16 (+ zero colsum for the fused-colsum scores pass)
  tofp16_kernel<<<MTOK * D_ / 4 / 256, 256, 0, stream>>>(
      (const float4*)x, (ushort4*)xh, MTOK * D_ / 4,
      (float4*)colsum, B_ * T_ / 4);

  // 2. transpose + concat W -> fp16
  wcat_t_kernel<<<dim3(32, 32, 3), 256, 0, stream>>>(Wq, Wk, Wv, Wt);

  // 3. fused QKV projection; V stored transposed in-epilogue (no vtrans)
  gemm8p<3><<<dim3(3072 / 256, MTOK / 128, 1), 512, 0, stream>>>(
      xh, Wt, QKVh, Vt, nullptr, D_, D_, D_, 3072, 0, 0, 0);

  // 4. scores = Q K^T, fp16 out + fused column-sum of exp(s-64)
  gemm8p<2><<<dim3(T_ / 256, T_ / 128, B_), 512, 0, stream>>>(
      QKVh, QKVh + 1024, scoresh, nullptr, colsum, D_, 3072, 3072, T_,
      (long)T_ * 3072, (long)T_ * 3072, (long)T_ * T_);

  // 5. u = 1/colsum
  sm_stats<<<B_ * T_ / 256, 256, 0, stream>>>(colsum, stats);

  // 6. out = exp(S-64)*u @ V  (BM=64/BN=256, 512 blocks = 2/CU)
  gemmPV<<<dim3(D_ / 256, T_ / 64, B_), 256, 0, stream>>>(
      scoresh, stats, Vt, out);
}